// Round 18
// baseline (45.027 us; speedup 1.0000x reference)
//
#include <hip/hip_runtime.h>
#include <math.h>

#define CC 30
#define NBATCH 4096
#define NIJ 49
#define NPAIR 1225            // 49 ij * 25 tail channels (c = 5..29)
#define THREADS 512
#define SLABF4 1470           // float4 count of a 4-batch slab of one tensor
#define SLABF  5880           // floats per 4-batch slab
#define NTBL   (6 * NPAIR + 4)   // 7354 u64 accumulators (6 stat arrays + 4 scalars)
#define SCALE  1099511627776.0   // 2^40
#define INVSCALE (1.0 / 1099511627776.0)

typedef unsigned long long u64;

// ws layout: tbl[NTBL] u64 at offset 0 (58.9 KB), zeroed by yolo_zero each call.

__global__ __launch_bounds__(512)
void yolo_zero(u64* __restrict__ tbl)
{
    const int i = blockIdx.x * 512 + threadIdx.x;
    if (i < NTBL) tbl[i] = 0ull;
}

__global__ __launch_bounds__(THREADS)
void yolo_main(const float* __restrict__ y, const float* __restrict__ yh,
               u64* __restrict__ tbl, int nwg)
{
    __shared__ __align__(16) float tY[2][SLABF];   // 2 x 23.5 KB
    __shared__ __align__(16) float tH[2][SLABF];   // 2 x 23.5 KB
    __shared__ float scr[4][8];

    const int tid = threadIdx.x;
    const int wg  = blockIdx.x;
    const int bpw = NBATCH / nwg;        // 16 for nwg=256
    const int nslab = bpw >> 2;          // 4

    const int i0 = tid, i1 = tid + 512;
    const int i2r = tid + 1024;
    const int i2  = (i2r < SLABF4) ? i2r : (SLABF4 - 1);
    const bool w2 = (i2r < SLABF4);

    int  ijv[3], cv[3], pr[3];
    bool val[3];
    #pragma unroll
    for (int i = 0; i < 3; i++) {
        int p = tid + i * THREADS;
        val[i] = (p < NPAIR);
        pr[i]  = p;
        int pp = val[i] ? p : 0;
        ijv[i] = pp / 25;
        cv[i]  = 5 + pp % 25;
    }

    float D0[3] = {0,0,0}, B0[3] = {0,0,0}, C0[3] = {0,0,0};
    float D1[3] = {0,0,0}, B1[3] = {0,0,0}, C1[3] = {0,0,0};
    float obj = 0.f, noobj = 0.f, coord = 0.f, tt = 0.f;

    const float4* Yg = (const float4*)y;
    const float4* Hg = (const float4*)yh;

    // prologue: stage slab 0 into buffer 0
    {
        const size_t f4 = (size_t)((wg * bpw) >> 2) * SLABF4;
        float4 a0 = Yg[f4+i0], a1 = Yg[f4+i1], a2 = Yg[f4+i2];
        float4 b0 = Hg[f4+i0], b1 = Hg[f4+i1], b2 = Hg[f4+i2];
        float4* dY = (float4*)tY[0];
        float4* dH = (float4*)tH[0];
        dY[i0] = a0; dY[i1] = a1; if (w2) dY[i2] = a2;
        dH[i0] = b0; dH[i1] = b1; if (w2) dH[i2] = b2;
    }
    __syncthreads();

    for (int s = 0; s < nslab; s++) {
        const float* cy = tY[s & 1];
        const float* ch = tH[s & 1];
        const bool pf = (s + 1 < nslab);
        float4 ry0, ry1, ry2, rh0, rh1, rh2;
        if (pf) {                 // issue next slab's loads; they fly during compute
            const size_t nf4 = (size_t)((wg * bpw + (s+1)*4) >> 2) * SLABF4;
            ry0 = Yg[nf4+i0]; ry1 = Yg[nf4+i1]; ry2 = Yg[nf4+i2];
            rh0 = Hg[nf4+i0]; rh1 = Hg[nf4+i1]; rh2 = Hg[nf4+i2];
        }

        // ---- pointwise: 196 cells in this slab ----
        if (tid < 4 * NIJ) {
            const int base = tid * CC;
            float y0 = cy[base],     h0 = ch[base];
            float y5 = cy[base + 5], h5 = ch[base + 5];
            float d0 = y0 - h0; d0 *= d0;
            float d5 = y5 - h5; d5 *= d5;
            const bool m0 = (y0 == 1.0f), m1 = (y5 == 1.0f);
            obj   += (m0 ? d0 : 0.f) + (m1 ? d5 : 0.f);
            noobj += (m0 ? 0.f : d0) + (m1 ? 0.f : d5);
            if (m0) {
                float a  = cy[base + 1] - ch[base + 1];
                float b2 = cy[base + 2] - ch[base + 2];
                float c1 = sqrtf(cy[base + 3]) - sqrtf(ch[base + 3]);
                float c2 = sqrtf(cy[base + 4]) - sqrtf(ch[base + 4]);
                coord += a * a + b2 * b2 + c1 * c1 + c2 * c2;
            }
            if (m1) {
                float a  = cy[base + 6] - ch[base + 6];
                float b2 = cy[base + 7] - ch[base + 7];
                float c1 = sqrtf(cy[base + 8]) - sqrtf(ch[base + 8]);
                float c2 = sqrtf(cy[base + 9]) - sqrtf(ch[base + 9]);
                coord += a * a + b2 * b2 + c1 * c1 + c2 * c2;
            }
        }

        // ---- slot phase: register accumulation ----
        #pragma unroll
        for (int b = 0; b < 4; b++) {
            #pragma unroll
            for (int i = 0; i < 3; i++) {
                if (!val[i]) continue;
                const int cb = b * 1470 + ijv[i] * CC;
                const float w0 = (cy[cb] == 1.0f) ? 1.f : 0.f;
                const float wk = (cv[i] >= 10 && cy[cb + 5] == 1.0f) ? 1.f : 0.f;
                const float t  = cy[cb + cv[i]];
                const float th = ch[cb + cv[i]];
                const float e  = __expf(th);
                const float te = t * e, ee = e * e, t2 = t * t;
                D0[i] = fmaf(e,  w0, D0[i]);
                B0[i] = fmaf(te, w0, B0[i]);
                C0[i] = fmaf(ee, w0, C0[i]);
                D1[i] = fmaf(e,  wk, D1[i]);
                B1[i] = fmaf(te, wk, B1[i]);
                C1[i] = fmaf(ee, wk, C1[i]);
                tt = fmaf(t2, w0 + wk, tt);
            }
        }

        // ---- write prefetched slab into the other buffer; ONE barrier per slab ----
        if (pf) {
            float4* dY = (float4*)tY[(s + 1) & 1];
            float4* dH = (float4*)tH[(s + 1) & 1];
            dY[i0] = ry0; dY[i1] = ry1; if (w2) dY[i2] = ry2;
            dH[i0] = rh0; dH[i1] = rh1; if (w2) dH[i2] = rh2;
        }
        __syncthreads();
    }

    // ---- per-slot u64 fixed-point atomics (deterministic: integer adds commute) ----
    #pragma unroll
    for (int i = 0; i < 3; i++) {
        if (!val[i]) continue;
        const int p = pr[i];
        atomicAdd(&tbl[p],             (u64)((double)D0[i] * SCALE));
        atomicAdd(&tbl[NPAIR + p],     (u64)((double)B0[i] * SCALE));
        atomicAdd(&tbl[2*NPAIR + p],   (u64)((double)C0[i] * SCALE));
        if (cv[i] >= 10) {
            atomicAdd(&tbl[3*NPAIR + p], (u64)((double)D1[i] * SCALE));
            atomicAdd(&tbl[4*NPAIR + p], (u64)((double)B1[i] * SCALE));
            atomicAdd(&tbl[5*NPAIR + p], (u64)((double)C1[i] * SCALE));
        }
    }

    // ---- scalar sums: shuffle -> LDS -> 4 u64 atomics per wg ----
    const int lane = tid & 63, wv = tid >> 6;
    #pragma unroll
    for (int off = 32; off > 0; off >>= 1) {
        obj   += __shfl_down(obj,   off);
        noobj += __shfl_down(noobj, off);
        coord += __shfl_down(coord, off);
        tt    += __shfl_down(tt,    off);
    }
    if (lane == 0) { scr[0][wv] = obj; scr[1][wv] = noobj; scr[2][wv] = coord; scr[3][wv] = tt; }
    __syncthreads();
    if (tid < 4) {
        float sacc = 0.f;
        #pragma unroll
        for (int w = 0; w < THREADS / 64; w++) sacc += scr[tid][w];
        atomicAdd(&tbl[6*NPAIR + tid], (u64)((double)sacc * SCALE));
    }
}

__global__ __launch_bounds__(1024)
void yolo_final(const u64* __restrict__ tbl, float* __restrict__ out)
{
    double v = 0.0;

    for (int s = threadIdx.x; s < NPAIR; s += 1024) {
        const int cidx = s % 25;
        double D0 = (double)tbl[s]           * INVSCALE;
        double B0 = (double)tbl[NPAIR + s]   * INVSCALE;
        double C0 = (double)tbl[2*NPAIR + s] * INVSCALE;
        if (D0 > 0.0) v += C0 / (D0 * D0) - 2.0 * B0 / D0;
        if (cidx >= 5) {
            double D1 = (double)tbl[3*NPAIR + s] * INVSCALE;
            double B1 = (double)tbl[4*NPAIR + s] * INVSCALE;
            double C1 = (double)tbl[5*NPAIR + s] * INVSCALE;
            if (D1 > 0.0) v += C1 / (D1 * D1) - 2.0 * B1 / D1;
        }
    }

    __shared__ double sred[16];
    #pragma unroll
    for (int off = 32; off > 0; off >>= 1) v += __shfl_down(v, off);
    const int lane = threadIdx.x & 63, wv = threadIdx.x >> 6;
    if (lane == 0) sred[wv] = v;
    __syncthreads();
    if (threadIdx.x == 0) {
        double tot = 0.0;
        #pragma unroll
        for (int w = 0; w < 16; w++) tot += sred[w];
        double obj   = (double)tbl[6*NPAIR + 0] * INVSCALE;
        double noobj = (double)tbl[6*NPAIR + 1] * INVSCALE;
        double coord = (double)tbl[6*NPAIR + 2] * INVSCALE;
        double tts   = (double)tbl[6*NPAIR + 3] * INVSCALE;
        double loss = obj + 0.5 * noobj + 5.0 * coord + tts + tot;
        out[0] = (float)(loss / (double)NBATCH);
    }
}

extern "C" void kernel_launch(void* const* d_in, const int* in_sizes, int n_in,
                              void* d_out, int out_size, void* d_ws, size_t ws_size,
                              hipStream_t stream)
{
    const float* y  = (const float*)d_in[0];
    const float* yh = (const float*)d_in[1];
    float* out = (float*)d_out;
    u64*   tbl = (u64*)d_ws;

    const int nwg = 256;
    yolo_zero<<<(NTBL + 511) / 512, 512, 0, stream>>>(tbl);
    yolo_main<<<nwg, THREADS, 0, stream>>>(y, yh, tbl, nwg);
    yolo_final<<<1, 1024, 0, stream>>>(tbl, out);
}

// Round 20
// 33.962 us; speedup vs baseline: 1.3258x; 1.3258x over previous
//
#include <hip/hip_runtime.h>
#include <math.h>

#define CC 30
#define NBATCH 4096
#define NIJ 49
#define NPAIR 1225            // 49 ij * 25 tail channels (c = 5..29)
#define PSTR 7352             // per-wg partial stride in floats (6*NPAIR=7350, padded to /4)
#define F4TOT (PSTR / 4)
#define THREADS 512
#define SLABF4 1470           // float4 count of a 4-batch slab of one tensor
#define SLABF  5880           // floats per 4-batch slab
#define NRED   232            // reduce grid = 29 x 8 blocks

// ws layout (NO memsets: ctr is zeroed by yolo_main each call; every other
// read location is written first):
//   offset 0      : scal[nwg][4]        (written by yolo_main)
//   offset 4096   : ctr (int)           (zeroed by yolo_main block 0)
//   offset 8192   : parts2[8][PSTR]     (written by yolo_reduce)
//   offset 243456 : parts[nwg][PSTR]    (written by yolo_main)

__global__ __launch_bounds__(THREADS)
void yolo_main(const float* __restrict__ y, const float* __restrict__ yh,
               float* __restrict__ scal, float* __restrict__ parts,
               int* __restrict__ ctr, int nwg)
{
    __shared__ __align__(16) float tY[2][SLABF];   // 2 x 23.5 KB
    __shared__ __align__(16) float tH[2][SLABF];   // 2 x 23.5 KB
    __shared__ float scr[4][8];

    const int tid = threadIdx.x;
    const int wg  = blockIdx.x;
    if (wg == 0 && tid == 0) *ctr = 0;   // arrival counter for yolo_reduce (poison-safe)

    const int bpw = NBATCH / nwg;        // 16 for nwg=256
    const int nslab = bpw >> 2;          // 4

    const int i0 = tid, i1 = tid + 512;
    const int i2r = tid + 1024;
    const int i2  = (i2r < SLABF4) ? i2r : (SLABF4 - 1);
    const bool w2 = (i2r < SLABF4);

    int  ijv[3], cv[3], pr[3];
    bool val[3];
    #pragma unroll
    for (int i = 0; i < 3; i++) {
        int p = tid + i * THREADS;
        val[i] = (p < NPAIR);
        pr[i]  = p;
        int pp = val[i] ? p : 0;
        ijv[i] = pp / 25;
        cv[i]  = 5 + pp % 25;
    }

    float D0[3] = {0,0,0}, B0[3] = {0,0,0}, C0[3] = {0,0,0};
    float D1[3] = {0,0,0}, B1[3] = {0,0,0}, C1[3] = {0,0,0};
    float obj = 0.f, noobj = 0.f, coord = 0.f, tt = 0.f;

    const float4* Yg = (const float4*)y;
    const float4* Hg = (const float4*)yh;

    // prologue: stage slab 0 into buffer 0
    {
        const size_t f4 = (size_t)((wg * bpw) >> 2) * SLABF4;
        float4 a0 = Yg[f4+i0], a1 = Yg[f4+i1], a2 = Yg[f4+i2];
        float4 b0 = Hg[f4+i0], b1 = Hg[f4+i1], b2 = Hg[f4+i2];
        float4* dY = (float4*)tY[0];
        float4* dH = (float4*)tH[0];
        dY[i0] = a0; dY[i1] = a1; if (w2) dY[i2] = a2;
        dH[i0] = b0; dH[i1] = b1; if (w2) dH[i2] = b2;
    }
    __syncthreads();

    for (int s = 0; s < nslab; s++) {
        const float* cy = tY[s & 1];
        const float* ch = tH[s & 1];
        const bool pf = (s + 1 < nslab);
        float4 ry0, ry1, ry2, rh0, rh1, rh2;
        if (pf) {                 // issue next slab's loads; they fly during compute
            const size_t nf4 = (size_t)((wg * bpw + (s+1)*4) >> 2) * SLABF4;
            ry0 = Yg[nf4+i0]; ry1 = Yg[nf4+i1]; ry2 = Yg[nf4+i2];
            rh0 = Hg[nf4+i0]; rh1 = Hg[nf4+i1]; rh2 = Hg[nf4+i2];
        }

        // ---- pointwise: 196 cells in this slab ----
        if (tid < 4 * NIJ) {
            const int base = tid * CC;
            float y0 = cy[base],     h0 = ch[base];
            float y5 = cy[base + 5], h5 = ch[base + 5];
            float d0 = y0 - h0; d0 *= d0;
            float d5 = y5 - h5; d5 *= d5;
            const bool m0 = (y0 == 1.0f), m1 = (y5 == 1.0f);
            obj   += (m0 ? d0 : 0.f) + (m1 ? d5 : 0.f);
            noobj += (m0 ? 0.f : d0) + (m1 ? 0.f : d5);
            if (m0) {
                float a  = cy[base + 1] - ch[base + 1];
                float b2 = cy[base + 2] - ch[base + 2];
                float c1 = sqrtf(cy[base + 3]) - sqrtf(ch[base + 3]);
                float c2 = sqrtf(cy[base + 4]) - sqrtf(ch[base + 4]);
                coord += a * a + b2 * b2 + c1 * c1 + c2 * c2;
            }
            if (m1) {
                float a  = cy[base + 6] - ch[base + 6];
                float b2 = cy[base + 7] - ch[base + 7];
                float c1 = sqrtf(cy[base + 8]) - sqrtf(ch[base + 8]);
                float c2 = sqrtf(cy[base + 9]) - sqrtf(ch[base + 9]);
                coord += a * a + b2 * b2 + c1 * c1 + c2 * c2;
            }
        }

        // ---- slot phase: register accumulation, no atomics ----
        #pragma unroll
        for (int b = 0; b < 4; b++) {
            #pragma unroll
            for (int i = 0; i < 3; i++) {
                if (!val[i]) continue;
                const int cb = b * 1470 + ijv[i] * CC;
                const float w0 = (cy[cb] == 1.0f) ? 1.f : 0.f;
                const float wk = (cv[i] >= 10 && cy[cb + 5] == 1.0f) ? 1.f : 0.f;
                const float t  = cy[cb + cv[i]];
                const float th = ch[cb + cv[i]];
                const float e  = __expf(th);
                const float te = t * e, ee = e * e, t2 = t * t;
                D0[i] = fmaf(e,  w0, D0[i]);
                B0[i] = fmaf(te, w0, B0[i]);
                C0[i] = fmaf(ee, w0, C0[i]);
                D1[i] = fmaf(e,  wk, D1[i]);
                B1[i] = fmaf(te, wk, B1[i]);
                C1[i] = fmaf(ee, wk, C1[i]);
                tt = fmaf(t2, w0 + wk, tt);
            }
        }

        // ---- write prefetched slab into the other buffer; ONE barrier per slab ----
        if (pf) {
            float4* dY = (float4*)tY[(s + 1) & 1];
            float4* dH = (float4*)tH[(s + 1) & 1];
            dY[i0] = ry0; dY[i1] = ry1; if (w2) dY[i2] = ry2;
            dH[i0] = rh0; dH[i1] = rh1; if (w2) dH[i2] = rh2;
        }
        __syncthreads();
    }

    // ---- per-wg partials: contiguous block, coalesced stores ----
    float* pp = parts + (size_t)wg * PSTR;
    #pragma unroll
    for (int i = 0; i < 3; i++) {
        if (!val[i]) continue;
        const int p = pr[i];
        pp[p]            = D0[i];
        pp[NPAIR + p]    = B0[i];
        pp[2*NPAIR + p]  = C0[i];
        pp[3*NPAIR + p]  = D1[i];   // zero when cv<10
        pp[4*NPAIR + p]  = B1[i];
        pp[5*NPAIR + p]  = C1[i];
    }

    // ---- scalar sums: shuffle -> LDS -> 4 floats per wg ----
    const int lane = tid & 63, wv = tid >> 6;
    #pragma unroll
    for (int off = 32; off > 0; off >>= 1) {
        obj   += __shfl_down(obj,   off);
        noobj += __shfl_down(noobj, off);
        coord += __shfl_down(coord, off);
        tt    += __shfl_down(tt,    off);
    }
    if (lane == 0) { scr[0][wv] = obj; scr[1][wv] = noobj; scr[2][wv] = coord; scr[3][wv] = tt; }
    __syncthreads();
    if (tid < 4) {
        float sacc = 0.f;
        #pragma unroll
        for (int w = 0; w < THREADS / 64; w++) sacc += scr[tid][w];
        scal[wg * 4 + tid] = sacc;
    }
}

// grid (29, 8) x 512: block (bx, cy) sums 64 float4-columns over 1/8 of the wgs,
// stores to parts2; the LAST arriving block folds parts2 + scal -> out (no 3rd kernel).
__global__ __launch_bounds__(512)
void yolo_reduce(const float* __restrict__ parts, float* __restrict__ parts2,
                 const float* __restrict__ scal, int* __restrict__ ctr,
                 float* __restrict__ out, int nwg)
{
    const int tid  = threadIdx.x;
    const int lane = tid & 63;                  // float4 column lane
    const int sub  = tid >> 6;                  // 0..7
    const int f4i  = blockIdx.x * 64 + lane;
    const int cy   = blockIdx.y;                // 0..7
    const int wpc  = nwg >> 3;                  // wgs per chunk (32 for nwg=256)
    const int wps  = wpc >> 3;                  // wgs per sub-group (4)

    float4 s = make_float4(0.f, 0.f, 0.f, 0.f);
    if (f4i < F4TOT) {
        const float* q = parts + (size_t)(cy * wpc + sub * wps) * PSTR + f4i * 4;
        for (int w = 0; w < wps; ++w) {
            float4 a = *(const float4*)q;
            s.x += a.x; s.y += a.y; s.z += a.z; s.w += a.w;
            q += PSTR;
        }
    }
    __shared__ float4 sred[8][64];
    sred[sub][lane] = s;
    __syncthreads();
    if (tid < 64 && f4i < F4TOT) {
        float4 t = sred[0][lane];
        #pragma unroll
        for (int c = 1; c < 8; c++) {
            float4 a = sred[c][lane];
            t.x += a.x; t.y += a.y; t.z += a.z; t.w += a.w;
        }
        *(float4*)(parts2 + (size_t)cy * PSTR + f4i * 4) = t;
    }

    // ---- last-block-done: one fence + one atomic per block (232 total) ----
    __syncthreads();
    __shared__ int islast;
    if (tid == 0) {
        __threadfence();                         // release this block's parts2 stores
        islast = (atomicAdd(ctr, 1) == NRED - 1);
    }
    __syncthreads();
    if (!islast) return;
    __threadfence();                             // acquire all blocks' parts2 stores

    // ---- final fold (bit-deterministic: fixed input, fixed order) ----
    float v = 0.f;
    for (int s2 = tid; s2 < NPAIR; s2 += 512) {
        const int cidx = s2 % 25;
        float D0 = 0, B0 = 0, C0 = 0, D1 = 0, B1 = 0, C1 = 0;
        #pragma unroll
        for (int c = 0; c < 8; c++) {
            const float* t = parts2 + (size_t)c * PSTR;
            D0 += t[s2];           B0 += t[NPAIR + s2];   C0 += t[2*NPAIR + s2];
            D1 += t[3*NPAIR + s2]; B1 += t[4*NPAIR + s2]; C1 += t[5*NPAIR + s2];
        }
        if (D0 > 0.f) v += C0 / (D0 * D0) - 2.f * B0 / D0;
        if (cidx >= 5 && D1 > 0.f) v += C1 / (D1 * D1) - 2.f * B1 / D1;
    }
    const float4* s4 = (const float4*)scal;
    for (int w = tid; w < nwg; w += 512) {
        float4 a = s4[w];
        v += a.x + 0.5f * a.y + 5.0f * a.z + a.w;
    }

    __shared__ float fred[8];
    #pragma unroll
    for (int off = 32; off > 0; off >>= 1) v += __shfl_down(v, off);
    if (lane == 0) fred[sub] = v;
    __syncthreads();
    if (tid == 0) {
        float tot = 0.f;
        #pragma unroll
        for (int w = 0; w < 8; w++) tot += fred[w];
        out[0] = tot / (float)NBATCH;
    }
}

extern "C" void kernel_launch(void* const* d_in, const int* in_sizes, int n_in,
                              void* d_out, int out_size, void* d_ws, size_t ws_size,
                              hipStream_t stream)
{
    const float* y  = (const float*)d_in[0];
    const float* yh = (const float*)d_in[1];
    float* out    = (float*)d_out;
    float* scal   = (float*)d_ws;
    int*   ctr    = (int*)((char*)d_ws + 4096);
    float* parts2 = (float*)((char*)d_ws + 8192);
    float* parts  = (float*)((char*)d_ws + 243456);

    const size_t per_wg = (size_t)PSTR * sizeof(float);   // 29.4 KB
    int nwg;
    if      (ws_size >= 243456 + 256 * per_wg) nwg = 256;
    else if (ws_size >= 243456 + 128 * per_wg) nwg = 128;
    else                                       nwg = 64;

    yolo_main<<<nwg, THREADS, 0, stream>>>(y, yh, scal, parts, ctr, nwg);
    dim3 g2((F4TOT + 63) / 64, 8);
    yolo_reduce<<<g2, 512, 0, stream>>>(parts, parts2, scal, ctr, out, nwg);
}